// Round 2
// baseline (1348.240 us; speedup 1.0000x reference)
//
#include <hip/hip_runtime.h>
#include <hip/hip_bf16.h>

typedef __hip_bfloat16 bf16;
typedef __attribute__((ext_vector_type(8))) short short8;
typedef __attribute__((ext_vector_type(4))) short short4v;
typedef __attribute__((ext_vector_type(4))) float f32x4;

#define NB 128
#define NH 128
#define NLQ 128
#define NLD 512
#define NEMB 300

__device__ __forceinline__ unsigned short bfbits(float x) {
    __hip_bfloat16 h = __float2bfloat16(x);
    return *reinterpret_cast<unsigned short*>(&h);
}

__device__ __forceinline__ float fast_tanh(float x) {
    x = fminf(9.f, fmaxf(-9.f, x));
    float e = __builtin_amdgcn_exp2f(x * 2.8853900817779268f); // e^{2x}
    return (e - 1.f) * __builtin_amdgcn_rcpf(e + 1.f);
}

// ---------------- Stage 0: pack conv weights to bf16 in MFMA staging order ----
// Wp layout per width: [chunk=t*10+cc][h(128)][c'(32)], c = cc*32+c' (c>=300 -> 0)
__global__ void pack_w(const float* __restrict__ cw0, const float* __restrict__ cw1,
                       const float* __restrict__ cw2, bf16* __restrict__ Wp)
{
    int widx = blockIdx.y;
    int W = widx + 2;
    int e = blockIdx.x * 256 + threadIdx.x;
    if (e >= W * 40960) return;
    int t = e / 40960;
    int rem = e - t * 40960;
    int cc = rem / 4096;
    int rem2 = rem - cc * 4096;
    int h = rem2 >> 5;
    int cp = rem2 & 31;
    int c = cc * 32 + cp;
    const float* cw = (widx == 0) ? cw0 : (widx == 1 ? cw1 : cw2);
    float v = (c < NEMB) ? cw[(h * NEMB + c) * W + t] : 0.f;
    size_t off = (widx == 0) ? 0 : (widx == 1 ? 81920 : 204800);
    Wp[off + e] = __float2bfloat16(v);
}

// ---------------- Stage 1: gather + conv + tanh + l2norm ----------------
// Grid 1920: bx%3 = width, bx/3 = 128 q-blocks + 512 d-blocks. 128(l)x128(h) tile.
// Xs staged once; B double-buffered with reg prefetch; 1 barrier / 32-K chunk.
__global__ __launch_bounds__(256, 1)
void conv_kernel(const int* __restrict__ q_tok, const int* __restrict__ d_tok,
                 const float* __restrict__ q_emb, const float* __restrict__ d_emb,
                 const bf16* __restrict__ Wp,
                 const float* __restrict__ cb0, const float* __restrict__ cb1,
                 const float* __restrict__ cb2,
                 bf16* __restrict__ qn, bf16* __restrict__ dn)
{
    __shared__ bf16 Xs[131][328];      // stride 328: frag reads 2-way (free)
    __shared__ bf16 Bs[2][128][40];
    __shared__ float ssq[2][128];

    int bx = blockIdx.x;
    int widx = bx % 3;
    int inner = bx / 3;
    int W = widx + 2;
    const bf16* wp = Wp + ((widx == 0) ? 0 : (widx == 1 ? 81920 : 204800));
    const float* cb = (widx == 0) ? cb0 : (widx == 1 ? cb1 : cb2);

    const int* toks; const float* emb; bf16* outp; int L, b, l0;
    if (inner < 128) {
        toks = q_tok; emb = q_emb; outp = qn + (size_t)widx * NB * NLQ * NH;
        L = NLQ; b = inner; l0 = 0;
    } else {
        int i = inner - 128;
        toks = d_tok; emb = d_emb; outp = dn + (size_t)widx * NB * NLD * NH;
        L = NLD; b = i >> 2; l0 = (i & 3) * 128;
    }

    int tid = threadIdx.x;
    int lane = tid & 63;
    int wv = tid >> 6, wr = wv >> 1, wc = wv & 1;

    const short8* wp8 = reinterpret_cast<const short8*>(wp);
    short8 pb0 = wp8[tid * 2], pb1 = wp8[tid * 2 + 1];   // chunk 0 prefetch

    // stage Xs (2 threads per row; rows >= L and cols >= 300 zeroed)
    {
        int half = tid & 1;
        int v0 = half ? 41 : 0, v1 = half ? 82 : 41;
        auto stage = [&](int r) {
            int l = l0 + r;
            bool valid = (l < L);
            int tok = valid ? toks[b * L + l] : 0;
            const float4* src = reinterpret_cast<const float4*>(emb + (size_t)tok * NEMB);
            for (int v = v0; v < v1; ++v) {
                float4 x = make_float4(0.f, 0.f, 0.f, 0.f);
                if (valid && v < 75) x = src[v];
                short4v o;
                o[0] = (short)bfbits(x.x); o[1] = (short)bfbits(x.y);
                o[2] = (short)bfbits(x.z); o[3] = (short)bfbits(x.w);
                *reinterpret_cast<short4v*>(&Xs[r][v * 4]) = o;
            }
        };
        stage(tid >> 1);
        if (tid < 6) stage(128 + (tid >> 1));
    }

    *reinterpret_cast<short8*>(&Bs[0][tid >> 1][(tid & 1) * 16]) = pb0;
    *reinterpret_cast<short8*>(&Bs[0][tid >> 1][(tid & 1) * 16 + 8]) = pb1;
    __syncthreads();

    f32x4 acc[4][4];
    #pragma unroll
    for (int m = 0; m < 4; ++m)
        #pragma unroll
        for (int n = 0; n < 4; ++n)
            acc[m][n] = (f32x4){0.f, 0.f, 0.f, 0.f};

    int nch = W * 10;
    int buf = 0, ch = 0;
    for (int t = 0; t < W; ++t) {
        for (int cc = 0; cc < 10; ++cc, ++ch) {
            short8 nb0, nb1;
            bool hn = (ch + 1 < nch);
            if (hn) {
                nb0 = wp8[(ch + 1) * 512 + tid * 2];
                nb1 = wp8[(ch + 1) * 512 + tid * 2 + 1];
            }
            short8 af[4], bv[4];
            #pragma unroll
            for (int m = 0; m < 4; ++m)
                af[m] = *reinterpret_cast<const short8*>(
                    &Xs[wr * 64 + m * 16 + (lane & 15) + t][cc * 32 + (lane >> 4) * 8]);
            #pragma unroll
            for (int n = 0; n < 4; ++n)
                bv[n] = *reinterpret_cast<const short8*>(
                    &Bs[buf][wc * 64 + n * 16 + (lane & 15)][(lane >> 4) * 8]);
            #pragma unroll
            for (int m = 0; m < 4; ++m)
                #pragma unroll
                for (int n = 0; n < 4; ++n)
                    acc[m][n] = __builtin_amdgcn_mfma_f32_16x16x32_bf16(af[m], bv[n], acc[m][n], 0, 0, 0);
            if (hn) {
                *reinterpret_cast<short8*>(&Bs[buf ^ 1][tid >> 1][(tid & 1) * 16]) = nb0;
                *reinterpret_cast<short8*>(&Bs[buf ^ 1][tid >> 1][(tid & 1) * 16 + 8]) = nb1;
            }
            __syncthreads();
            buf ^= 1;
        }
    }

    // epilogue: bias + tanh, shuffle row-norm, write bf16
    float ss[4][4];
    #pragma unroll
    for (int m = 0; m < 4; ++m)
        #pragma unroll
        for (int i = 0; i < 4; ++i) ss[m][i] = 0.f;

    #pragma unroll
    for (int n = 0; n < 4; ++n) {
        float bias = cb[wc * 64 + n * 16 + (lane & 15)];
        #pragma unroll
        for (int m = 0; m < 4; ++m)
            #pragma unroll
            for (int i = 0; i < 4; ++i) {
                float v = fast_tanh(acc[m][n][i] + bias);
                acc[m][n][i] = v;
                ss[m][i] += v * v;
            }
    }
    #pragma unroll
    for (int m = 0; m < 4; ++m)
        #pragma unroll
        for (int i = 0; i < 4; ++i) {
            float s = ss[m][i];
            s += __shfl_xor(s, 1); s += __shfl_xor(s, 2);
            s += __shfl_xor(s, 4); s += __shfl_xor(s, 8);
            ss[m][i] = s;
        }
    if ((lane & 15) == 0) {
        #pragma unroll
        for (int m = 0; m < 4; ++m)
            #pragma unroll
            for (int i = 0; i < 4; ++i)
                ssq[wc][wr * 64 + m * 16 + (lane >> 4) * 4 + i] = ss[m][i];
    }
    __syncthreads();
    #pragma unroll
    for (int m = 0; m < 4; ++m)
        #pragma unroll
        for (int i = 0; i < 4; ++i) {
            int row = wr * 64 + m * 16 + (lane >> 4) * 4 + i;
            float s2 = ssq[0][row] + ssq[1][row];
            float sc = 1.f / fmaxf(sqrtf(s2), 1e-12f);
            bf16* dst = outp + ((size_t)(b * L + l0 + row)) * NH;
            #pragma unroll
            for (int n = 0; n < 4; ++n) {
                int col = wc * 64 + n * 16 + (lane & 15);
                dst[col] = __float2bfloat16(acc[m][n][i] * sc);
            }
        }
}

// ---------------- Stage 2: S^T = D*Q^T, pooling fused on registers ----------
__global__ __launch_bounds__(256, 1)
void sim_kernel(const bf16* __restrict__ qn, const bf16* __restrict__ dn,
                float* __restrict__ phi)
{
    __shared__ bf16 Ds[128][136];
    __shared__ float red[2][128][12];
    __shared__ float wsum[2][11];

    int blk = blockIdx.x;
    int b = blk / 9;
    int pair = blk - b * 9;
    int qi = pair / 3, di = pair - qi * 3;

    int tid = threadIdx.x, lane = tid & 63, wv = tid >> 6, wr = wv >> 1, wc = wv & 1;

    const bf16* qbase = qn + ((size_t)qi * NB + b) * (NLQ * NH);
    const bf16* dbase = dn + ((size_t)di * NB + b) * (NLD * NH);

    // Q fragments (B operand) held in registers: col(lq), k = kc*32+(lane>>4)*8
    short8 bq[4][4];
    #pragma unroll
    for (int n = 0; n < 4; ++n)
        #pragma unroll
        for (int kc = 0; kc < 4; ++kc)
            bq[n][kc] = *reinterpret_cast<const short8*>(
                qbase + (size_t)(wc * 64 + n * 16 + (lane & 15)) * NH + kc * 32 + (lane >> 4) * 8);

    int r = tid >> 1, h0 = (tid & 1) * 64;
    short8 st[8];
    #pragma unroll
    for (int v = 0; v < 8; ++v)
        st[v] = *reinterpret_cast<const short8*>(dbase + (size_t)r * NH + h0 + v * 8);
    #pragma unroll
    for (int v = 0; v < 8; ++v)
        *reinterpret_cast<short8*>(&Ds[r][h0 + v * 8]) = st[v];
    __syncthreads();

    float sums[4][11];
    #pragma unroll
    for (int n = 0; n < 4; ++n)
        #pragma unroll
        for (int k = 0; k < 11; ++k) sums[n][k] = 0.f;

    for (int cc = 0; cc < 4; ++cc) {
        f32x4 acc[4][4];
        #pragma unroll
        for (int m = 0; m < 4; ++m)
            #pragma unroll
            for (int n = 0; n < 4; ++n)
                acc[m][n] = (f32x4){0.f, 0.f, 0.f, 0.f};

        #pragma unroll
        for (int kc = 0; kc < 4; ++kc) {
            short8 af[4];
            #pragma unroll
            for (int m = 0; m < 4; ++m)
                af[m] = *reinterpret_cast<const short8*>(
                    &Ds[wr * 64 + m * 16 + (lane & 15)][kc * 32 + (lane >> 4) * 8]);
            #pragma unroll
            for (int m = 0; m < 4; ++m)
                #pragma unroll
                for (int n = 0; n < 4; ++n)
                    acc[m][n] = __builtin_amdgcn_mfma_f32_16x16x32_bf16(af[m], bq[n][kc], acc[m][n], 0, 0, 0);
        }
        if (cc < 3) {
            #pragma unroll
            for (int v = 0; v < 8; ++v)
                st[v] = *reinterpret_cast<const short8*>(
                    dbase + (size_t)((cc + 1) * 128 + r) * NH + h0 + v * 8);
        }
        // pooling on registers; arg = -50/ln2*(x-mu)^2 via poly; k=10 in diff form
        #pragma unroll
        for (int n = 0; n < 4; ++n)
            #pragma unroll
            for (int m = 0; m < 4; ++m)
                #pragma unroll
                for (int i = 0; i < 4; ++i) {
                    float x = acc[m][n][i];
                    float ax2 = x * x * (-72.134752f);
                    #pragma unroll
                    for (int k = 0; k < 10; ++k) {
                        float mu = -0.9f + 0.2f * k;
                        float arg = ax2 + fmaf(144.26950408f * mu, x, -72.134752f * mu * mu);
                        sums[n][k] += __builtin_amdgcn_exp2f(arg);
                    }
                    float d = x - 1.0f;
                    sums[n][10] += __builtin_amdgcn_exp2f(d * d * (-721347.52f));
                }
        __syncthreads();
        if (cc < 3) {
            #pragma unroll
            for (int v = 0; v < 8; ++v)
                *reinterpret_cast<short8*>(&Ds[r][h0 + v * 8]) = st[v];
            __syncthreads();
        }
    }

    // reduce over lane-groups (ld within wave-half), combine wr halves, log1p, sum lq
    #pragma unroll
    for (int n = 0; n < 4; ++n)
        #pragma unroll
        for (int k = 0; k < 11; ++k) {
            float s = sums[n][k];
            s += __shfl_xor(s, 16);
            s += __shfl_xor(s, 32);
            sums[n][k] = s;
        }
    if ((lane >> 4) == 0) {
        #pragma unroll
        for (int n = 0; n < 4; ++n)
            #pragma unroll
            for (int k = 0; k < 11; ++k)
                red[wr][wc * 64 + n * 16 + (lane & 15)][k] = sums[n][k];
    }
    __syncthreads();
    if (tid < 128) {
        float lv[11];
        #pragma unroll
        for (int k = 0; k < 11; ++k)
            lv[k] = log1pf(red[0][tid][k] + red[1][tid][k]);
        #pragma unroll
        for (int k = 0; k < 11; ++k) {
            float s = lv[k];
            s += __shfl_xor(s, 1); s += __shfl_xor(s, 2); s += __shfl_xor(s, 4);
            s += __shfl_xor(s, 8); s += __shfl_xor(s, 16); s += __shfl_xor(s, 32);
            lv[k] = s;
        }
        if ((tid & 63) == 0) {
            #pragma unroll
            for (int k = 0; k < 11; ++k) wsum[tid >> 6][k] = lv[k];
        }
    }
    __syncthreads();
    if (tid < 11) phi[b * 99 + pair * 11 + tid] = wsum[0][tid] + wsum[1][tid];
}

// ---------------- Stage 3: final linear ----------------
__global__ void final_kernel(const float* __restrict__ phi, const float* __restrict__ ow,
                             const float* __restrict__ obias, float* __restrict__ out)
{
    int b = threadIdx.x;
    float s = obias[0];
    #pragma unroll
    for (int j = 0; j < 99; ++j) s += phi[b * 99 + j] * ow[j];
    out[b] = s;
}

extern "C" void kernel_launch(void* const* d_in, const int* in_sizes, int n_in,
                              void* d_out, int out_size, void* d_ws, size_t ws_size,
                              hipStream_t stream)
{
    const int*   query = (const int*)d_in[0];
    const int*   doc   = (const int*)d_in[1];
    const float* q_emb = (const float*)d_in[2];
    const float* d_emb = (const float*)d_in[3];
    const float* out_w = (const float*)d_in[4];
    const float* out_b = (const float*)d_in[5];
    const float* cw0 = (const float*)d_in[6];
    const float* cb0 = (const float*)d_in[7];
    const float* cw1 = (const float*)d_in[8];
    const float* cb1 = (const float*)d_in[9];
    const float* cw2 = (const float*)d_in[10];
    const float* cb2 = (const float*)d_in[11];

    const size_t QN = (size_t)NB * NLQ * NH;
    const size_t DN = (size_t)NB * NLD * NH;

    bf16* Wp = (bf16*)d_ws;                 // 368640 bf16
    bf16* qn = Wp + 368640;
    bf16* dn = qn + 3 * QN;
    float* phi = (float*)(dn + 3 * DN);

    pack_w<<<dim3(640, 3), 256, 0, stream>>>(cw0, cw1, cw2, Wp);
    conv_kernel<<<1920, 256, 0, stream>>>(query, doc, q_emb, d_emb, Wp, cb0, cb1, cb2, qn, dn);
    sim_kernel<<<NB * 9, 256, 0, stream>>>(qn, dn, phi);
    final_kernel<<<1, 128, 0, stream>>>(phi, out_w, out_b, (float*)d_out);
}

// Round 3
// 447.863 us; speedup vs baseline: 3.0104x; 3.0104x over previous
//
#include <hip/hip_runtime.h>
#include <hip/hip_bf16.h>

typedef __hip_bfloat16 bf16;
typedef __attribute__((ext_vector_type(8))) short short8;
typedef __attribute__((ext_vector_type(4))) short short4v;
typedef __attribute__((ext_vector_type(4))) float f32x4;

#define NB 128
#define NH 128
#define NLQ 128
#define NLD 512
#define NEMB 300

__device__ __forceinline__ unsigned short bfbits(float x) {
    __hip_bfloat16 h = __float2bfloat16(x);
    return *reinterpret_cast<unsigned short*>(&h);
}

__device__ __forceinline__ float fast_tanh(float x) {
    x = fminf(9.f, fmaxf(-9.f, x));
    float e = __builtin_amdgcn_exp2f(x * 2.8853900817779268f); // e^{2x}
    return (e - 1.f) * __builtin_amdgcn_rcpf(e + 1.f);
}

// ---------------- Stage 0: pack conv weights to bf16 in MFMA staging order ----
__global__ void pack_w(const float* __restrict__ cw0, const float* __restrict__ cw1,
                       const float* __restrict__ cw2, bf16* __restrict__ Wp)
{
    int widx = blockIdx.y;
    int W = widx + 2;
    int e = blockIdx.x * 256 + threadIdx.x;
    if (e >= W * 40960) return;
    int t = e / 40960;
    int rem = e - t * 40960;
    int cc = rem / 4096;
    int rem2 = rem - cc * 4096;
    int h = rem2 >> 5;
    int cp = rem2 & 31;
    int c = cc * 32 + cp;
    const float* cw = (widx == 0) ? cw0 : (widx == 1 ? cw1 : cw2);
    float v = (c < NEMB) ? cw[(h * NEMB + c) * W + t] : 0.f;
    size_t off = (widx == 0) ? 0 : (widx == 1 ? 81920 : 204800);
    Wp[off + e] = __float2bfloat16(v);
}

// ---------------- Stage 1: gather + conv + tanh + l2norm ----------------
__global__ __launch_bounds__(256, 1)
void conv_kernel(const int* __restrict__ q_tok, const int* __restrict__ d_tok,
                 const float* __restrict__ q_emb, const float* __restrict__ d_emb,
                 const bf16* __restrict__ Wp,
                 const float* __restrict__ cb0, const float* __restrict__ cb1,
                 const float* __restrict__ cb2,
                 bf16* __restrict__ qn, bf16* __restrict__ dn)
{
    __shared__ bf16 Xs[131][328];
    __shared__ bf16 Bs[2][128][40];
    __shared__ float ssq[2][128];

    int bx = blockIdx.x;
    int widx = bx % 3;
    int inner = bx / 3;
    int W = widx + 2;
    const bf16* wp = Wp + ((widx == 0) ? 0 : (widx == 1 ? 81920 : 204800));
    const float* cb = (widx == 0) ? cb0 : (widx == 1 ? cb1 : cb2);

    const int* toks; const float* emb; bf16* outp; int L, b, l0;
    if (inner < 128) {
        toks = q_tok; emb = q_emb; outp = qn + (size_t)widx * NB * NLQ * NH;
        L = NLQ; b = inner; l0 = 0;
    } else {
        int i = inner - 128;
        toks = d_tok; emb = d_emb; outp = dn + (size_t)widx * NB * NLD * NH;
        L = NLD; b = i >> 2; l0 = (i & 3) * 128;
    }

    int tid = threadIdx.x;
    int lane = tid & 63;
    int wv = tid >> 6, wr = wv >> 1, wc = wv & 1;

    const short8* wp8 = reinterpret_cast<const short8*>(wp);
    short8 pb0 = wp8[tid * 2], pb1 = wp8[tid * 2 + 1];

    {
        int half = tid & 1;
        int v0 = half ? 41 : 0, v1 = half ? 82 : 41;
        auto stage = [&](int r) {
            int l = l0 + r;
            bool valid = (l < L);
            int tok = valid ? toks[b * L + l] : 0;
            const float4* src = reinterpret_cast<const float4*>(emb + (size_t)tok * NEMB);
            for (int v = v0; v < v1; ++v) {
                float4 x = make_float4(0.f, 0.f, 0.f, 0.f);
                if (valid && v < 75) x = src[v];
                short4v o;
                o[0] = (short)bfbits(x.x); o[1] = (short)bfbits(x.y);
                o[2] = (short)bfbits(x.z); o[3] = (short)bfbits(x.w);
                *reinterpret_cast<short4v*>(&Xs[r][v * 4]) = o;
            }
        };
        stage(tid >> 1);
        if (tid < 6) stage(128 + (tid >> 1));
    }

    *reinterpret_cast<short8*>(&Bs[0][tid >> 1][(tid & 1) * 16]) = pb0;
    *reinterpret_cast<short8*>(&Bs[0][tid >> 1][(tid & 1) * 16 + 8]) = pb1;
    __syncthreads();

    f32x4 acc[4][4];
    #pragma unroll
    for (int m = 0; m < 4; ++m)
        #pragma unroll
        for (int n = 0; n < 4; ++n)
            acc[m][n] = (f32x4){0.f, 0.f, 0.f, 0.f};

    int nch = W * 10;
    int buf = 0, ch = 0;
    for (int t = 0; t < W; ++t) {
        for (int cc = 0; cc < 10; ++cc, ++ch) {
            short8 nb0, nb1;
            bool hn = (ch + 1 < nch);
            if (hn) {
                nb0 = wp8[(ch + 1) * 512 + tid * 2];
                nb1 = wp8[(ch + 1) * 512 + tid * 2 + 1];
            }
            short8 af[4], bv[4];
            #pragma unroll
            for (int m = 0; m < 4; ++m)
                af[m] = *reinterpret_cast<const short8*>(
                    &Xs[wr * 64 + m * 16 + (lane & 15) + t][cc * 32 + (lane >> 4) * 8]);
            #pragma unroll
            for (int n = 0; n < 4; ++n)
                bv[n] = *reinterpret_cast<const short8*>(
                    &Bs[buf][wc * 64 + n * 16 + (lane & 15)][(lane >> 4) * 8]);
            #pragma unroll
            for (int m = 0; m < 4; ++m)
                #pragma unroll
                for (int n = 0; n < 4; ++n)
                    acc[m][n] = __builtin_amdgcn_mfma_f32_16x16x32_bf16(af[m], bv[n], acc[m][n], 0, 0, 0);
            if (hn) {
                *reinterpret_cast<short8*>(&Bs[buf ^ 1][tid >> 1][(tid & 1) * 16]) = nb0;
                *reinterpret_cast<short8*>(&Bs[buf ^ 1][tid >> 1][(tid & 1) * 16 + 8]) = nb1;
            }
            __syncthreads();
            buf ^= 1;
        }
    }

    float ss[4][4];
    #pragma unroll
    for (int m = 0; m < 4; ++m)
        #pragma unroll
        for (int i = 0; i < 4; ++i) ss[m][i] = 0.f;

    #pragma unroll
    for (int n = 0; n < 4; ++n) {
        float bias = cb[wc * 64 + n * 16 + (lane & 15)];
        #pragma unroll
        for (int m = 0; m < 4; ++m)
            #pragma unroll
            for (int i = 0; i < 4; ++i) {
                float v = fast_tanh(acc[m][n][i] + bias);
                acc[m][n][i] = v;
                ss[m][i] += v * v;
            }
    }
    #pragma unroll
    for (int m = 0; m < 4; ++m)
        #pragma unroll
        for (int i = 0; i < 4; ++i) {
            float s = ss[m][i];
            s += __shfl_xor(s, 1); s += __shfl_xor(s, 2);
            s += __shfl_xor(s, 4); s += __shfl_xor(s, 8);
            ss[m][i] = s;
        }
    if ((lane & 15) == 0) {
        #pragma unroll
        for (int m = 0; m < 4; ++m)
            #pragma unroll
            for (int i = 0; i < 4; ++i)
                ssq[wc][wr * 64 + m * 16 + (lane >> 4) * 4 + i] = ss[m][i];
    }
    __syncthreads();
    #pragma unroll
    for (int m = 0; m < 4; ++m)
        #pragma unroll
        for (int i = 0; i < 4; ++i) {
            int row = wr * 64 + m * 16 + (lane >> 4) * 4 + i;
            float s2 = ssq[0][row] + ssq[1][row];
            float sc = 1.f / fmaxf(sqrtf(s2), 1e-12f);
            bf16* dst = outp + ((size_t)(b * L + l0 + row)) * NH;
            #pragma unroll
            for (int n = 0; n < 4; ++n) {
                int col = wc * 64 + n * 16 + (lane & 15);
                dst[col] = __float2bfloat16(acc[m][n][i] * sc);
            }
        }
}

// ---------------- Stage 2: S^T = D*Q^T, pooling fused on registers ----------
// Q in LDS (staged once). D single-buffer; next-chunk loads issued before the
// pooling block, LDS-written after it (latency hidden under ~700 exp2/thread).
__global__ __launch_bounds__(256, 2)
void sim_kernel(const bf16* __restrict__ qn, const bf16* __restrict__ dn,
                float* __restrict__ phi)
{
    __shared__ bf16 Qs[128][136];
    __shared__ bf16 Ds[128][136];
    __shared__ float red[2][128][11];
    __shared__ float wsum[2][11];

    int blk = blockIdx.x;
    int b = blk / 9;
    int pair = blk - b * 9;
    int qi = pair / 3, di = pair - qi * 3;

    int tid = threadIdx.x, lane = tid & 63, wv = tid >> 6, wr = wv >> 1, wc = wv & 1;

    const bf16* qbase = qn + ((size_t)qi * NB + b) * (NLQ * NH);
    const bf16* dbase = dn + ((size_t)di * NB + b) * (NLD * NH);

    int r = tid >> 1, h0 = (tid & 1) * 64;

    // stage Q once
    #pragma unroll
    for (int v = 0; v < 8; ++v)
        *reinterpret_cast<short8*>(&Qs[r][h0 + v * 8]) =
            *reinterpret_cast<const short8*>(qbase + (size_t)r * NH + h0 + v * 8);

    // stage D chunk 0
    {
        short8 st[8];
        #pragma unroll
        for (int v = 0; v < 8; ++v)
            st[v] = *reinterpret_cast<const short8*>(dbase + (size_t)r * NH + h0 + v * 8);
        #pragma unroll
        for (int v = 0; v < 8; ++v)
            *reinterpret_cast<short8*>(&Ds[r][h0 + v * 8]) = st[v];
    }
    __syncthreads();

    float sums[4][11];
    #pragma unroll
    for (int n = 0; n < 4; ++n)
        #pragma unroll
        for (int k = 0; k < 11; ++k) sums[n][k] = 0.f;

    for (int cc = 0; cc < 4; ++cc) {
        f32x4 acc[4][4];
        #pragma unroll
        for (int m = 0; m < 4; ++m)
            #pragma unroll
            for (int n = 0; n < 4; ++n)
                acc[m][n] = (f32x4){0.f, 0.f, 0.f, 0.f};

        #pragma unroll
        for (int kc = 0; kc < 4; ++kc) {
            short8 af[4], bq[4];
            #pragma unroll
            for (int m = 0; m < 4; ++m)
                af[m] = *reinterpret_cast<const short8*>(
                    &Ds[wr * 64 + m * 16 + (lane & 15)][kc * 32 + (lane >> 4) * 8]);
            #pragma unroll
            for (int n = 0; n < 4; ++n)
                bq[n] = *reinterpret_cast<const short8*>(
                    &Qs[wc * 64 + n * 16 + (lane & 15)][kc * 32 + (lane >> 4) * 8]);
            #pragma unroll
            for (int m = 0; m < 4; ++m)
                #pragma unroll
                for (int n = 0; n < 4; ++n)
                    acc[m][n] = __builtin_amdgcn_mfma_f32_16x16x32_bf16(af[m], bq[n], acc[m][n], 0, 0, 0);
        }
        __syncthreads();   // all waves done reading Ds; safe to overwrite after pooling

        short8 st[8];
        if (cc < 3) {
            #pragma unroll
            for (int v = 0; v < 8; ++v)
                st[v] = *reinterpret_cast<const short8*>(
                    dbase + (size_t)((cc + 1) * 128 + r) * NH + h0 + v * 8);
        }

        // pooling on registers (no LDS) — hides the in-flight D loads
        #pragma unroll
        for (int n = 0; n < 4; ++n)
            #pragma unroll
            for (int m = 0; m < 4; ++m)
                #pragma unroll
                for (int i = 0; i < 4; ++i) {
                    float x = acc[m][n][i];
                    float ax2 = x * x * (-72.134752f);
                    #pragma unroll
                    for (int k = 0; k < 10; ++k) {
                        float mu = -0.9f + 0.2f * k;
                        float arg = ax2 + fmaf(144.26950408f * mu, x, -72.134752f * mu * mu);
                        sums[n][k] += __builtin_amdgcn_exp2f(arg);
                    }
                    float d = x - 1.0f;
                    sums[n][10] += __builtin_amdgcn_exp2f(d * d * (-721347.52f));
                }

        if (cc < 3) {
            #pragma unroll
            for (int v = 0; v < 8; ++v)
                *reinterpret_cast<short8*>(&Ds[r][h0 + v * 8]) = st[v];
            __syncthreads();
        }
    }

    #pragma unroll
    for (int n = 0; n < 4; ++n)
        #pragma unroll
        for (int k = 0; k < 11; ++k) {
            float s = sums[n][k];
            s += __shfl_xor(s, 16);
            s += __shfl_xor(s, 32);
            sums[n][k] = s;
        }
    if ((lane >> 4) == 0) {
        #pragma unroll
        for (int n = 0; n < 4; ++n)
            #pragma unroll
            for (int k = 0; k < 11; ++k)
                red[wr][wc * 64 + n * 16 + (lane & 15)][k] = sums[n][k];
    }
    __syncthreads();
    if (tid < 128) {
        float lv[11];
        #pragma unroll
        for (int k = 0; k < 11; ++k)
            lv[k] = log1pf(red[0][tid][k] + red[1][tid][k]);
        #pragma unroll
        for (int k = 0; k < 11; ++k) {
            float s = lv[k];
            s += __shfl_xor(s, 1); s += __shfl_xor(s, 2); s += __shfl_xor(s, 4);
            s += __shfl_xor(s, 8); s += __shfl_xor(s, 16); s += __shfl_xor(s, 32);
            lv[k] = s;
        }
        if ((tid & 63) == 0) {
            #pragma unroll
            for (int k = 0; k < 11; ++k) wsum[tid >> 6][k] = lv[k];
        }
    }
    __syncthreads();
    if (tid < 11) phi[b * 99 + pair * 11 + tid] = wsum[0][tid] + wsum[1][tid];
}

// ---------------- Stage 3: final linear ----------------
__global__ void final_kernel(const float* __restrict__ phi, const float* __restrict__ ow,
                             const float* __restrict__ obias, float* __restrict__ out)
{
    int b = threadIdx.x;
    float s = obias[0];
    #pragma unroll
    for (int j = 0; j < 99; ++j) s += phi[b * 99 + j] * ow[j];
    out[b] = s;
}

extern "C" void kernel_launch(void* const* d_in, const int* in_sizes, int n_in,
                              void* d_out, int out_size, void* d_ws, size_t ws_size,
                              hipStream_t stream)
{
    const int*   query = (const int*)d_in[0];
    const int*   doc   = (const int*)d_in[1];
    const float* q_emb = (const float*)d_in[2];
    const float* d_emb = (const float*)d_in[3];
    const float* out_w = (const float*)d_in[4];
    const float* out_b = (const float*)d_in[5];
    const float* cw0 = (const float*)d_in[6];
    const float* cb0 = (const float*)d_in[7];
    const float* cw1 = (const float*)d_in[8];
    const float* cb1 = (const float*)d_in[9];
    const float* cw2 = (const float*)d_in[10];
    const float* cb2 = (const float*)d_in[11];

    const size_t QN = (size_t)NB * NLQ * NH;
    const size_t DN = (size_t)NB * NLD * NH;

    bf16* Wp = (bf16*)d_ws;
    bf16* qn = Wp + 368640;
    bf16* dn = qn + 3 * QN;
    float* phi = (float*)(dn + 3 * DN);

    pack_w<<<dim3(640, 3), 256, 0, stream>>>(cw0, cw1, cw2, Wp);
    conv_kernel<<<1920, 256, 0, stream>>>(query, doc, q_emb, d_emb, Wp, cb0, cb1, cb2, qn, dn);
    sim_kernel<<<NB * 9, 256, 0, stream>>>(qn, dn, phi);
    final_kernel<<<1, 128, 0, stream>>>(phi, out_w, out_b, (float*)d_out);
}

// Round 4
// 399.067 us; speedup vs baseline: 3.3785x; 1.1223x over previous
//
#include <hip/hip_runtime.h>
#include <hip/hip_bf16.h>

typedef __hip_bfloat16 bf16;
typedef __attribute__((ext_vector_type(8))) short short8;
typedef __attribute__((ext_vector_type(4))) short short4v;
typedef __attribute__((ext_vector_type(4))) float f32x4;

#define NB 128
#define NH 128
#define NLQ 128
#define NLD 512
#define NEMB 300

__device__ __forceinline__ unsigned short bfbits(float x) {
    __hip_bfloat16 h = __float2bfloat16(x);
    return *reinterpret_cast<unsigned short*>(&h);
}

__device__ __forceinline__ float fast_tanh(float x) {
    x = fminf(9.f, fmaxf(-9.f, x));
    float e = __builtin_amdgcn_exp2f(x * 2.8853900817779268f); // e^{2x}
    return (e - 1.f) * __builtin_amdgcn_rcpf(e + 1.f);
}

// ---------------- Stage 0: pack conv weights to bf16 in MFMA staging order ----
// layout per width: [chunk=t*10+cc][h(128)][c'(32)]
__global__ void pack_w(const float* __restrict__ cw0, const float* __restrict__ cw1,
                       const float* __restrict__ cw2, bf16* __restrict__ Wp)
{
    int widx = blockIdx.y;
    int W = widx + 2;
    int e = blockIdx.x * 256 + threadIdx.x;
    if (e >= W * 40960) return;
    int t = e / 40960;
    int rem = e - t * 40960;
    int cc = rem / 4096;
    int rem2 = rem - cc * 4096;
    int h = rem2 >> 5;
    int cp = rem2 & 31;
    int c = cc * 32 + cp;
    const float* cw = (widx == 0) ? cw0 : (widx == 1 ? cw1 : cw2);
    float v = (c < NEMB) ? cw[(h * NEMB + c) * W + t] : 0.f;
    size_t off = (widx == 0) ? 0 : (widx == 1 ? 81920 : 204800);
    Wp[off + e] = __float2bfloat16(v);
}

// ---------------- Stage 1: gather + conv + tanh + l2norm ----------------
// 512 threads = 8 waves (2/SIMD), wave grid 2(r)x4(c); 128x128 tile; X staged once.
__global__ __launch_bounds__(512, 1)
void conv_kernel(const int* __restrict__ q_tok, const int* __restrict__ d_tok,
                 const float* __restrict__ q_emb, const float* __restrict__ d_emb,
                 const bf16* __restrict__ Wp,
                 const float* __restrict__ cb0, const float* __restrict__ cb1,
                 const float* __restrict__ cb2,
                 bf16* __restrict__ qn, bf16* __restrict__ dn)
{
    __shared__ bf16 Xs[131][328];       // 85.9 KB; frag reads 2-way (free)
    __shared__ bf16 Bs[2][128][36];     // 18.4 KB; stride 36 -> 2-way reads
    __shared__ float ssq[4][128];

    int bx = blockIdx.x;
    int widx = bx % 3;
    int inner = bx / 3;
    int W = widx + 2;
    const bf16* wp = Wp + ((widx == 0) ? 0 : (widx == 1 ? 81920 : 204800));
    const float* cb = (widx == 0) ? cb0 : (widx == 1 ? cb1 : cb2);

    const int* toks; const float* emb; bf16* outp; int L, b, l0;
    if (inner < 128) {
        toks = q_tok; emb = q_emb; outp = qn + (size_t)widx * NB * NLQ * NH;
        L = NLQ; b = inner; l0 = 0;
    } else {
        int i = inner - 128;
        toks = d_tok; emb = d_emb; outp = dn + (size_t)widx * NB * NLD * NH;
        L = NLD; b = i >> 2; l0 = (i & 3) * 128;
    }

    int tid = threadIdx.x;
    int lane = tid & 63;
    int wv = tid >> 6;
    int wr = wv >> 2, wc = wv & 3;

    const short8* wp8 = reinterpret_cast<const short8*>(wp);
    short8 pb = wp8[tid];   // chunk 0 prefetch (chunk = 512 short8)

    // stage Xs: 4 threads/row; rows >= L and cols >= 300 zeroed
    {
        int sub = tid & 3;
        int v0 = sub * 19, v1 = (sub == 3) ? 75 : (sub * 19 + 19);
        auto stage = [&](int r) {
            int l = l0 + r;
            bool valid = (l < L);
            int tok = valid ? toks[b * L + l] : 0;
            const float4* src = reinterpret_cast<const float4*>(emb + (size_t)tok * NEMB);
            for (int v = v0; v < v1; ++v) {
                float4 x = make_float4(0.f, 0.f, 0.f, 0.f);
                if (valid) x = src[v];
                short4v o;
                o[0] = (short)bfbits(x.x); o[1] = (short)bfbits(x.y);
                o[2] = (short)bfbits(x.z); o[3] = (short)bfbits(x.w);
                *reinterpret_cast<short4v*>(&Xs[r][v * 4]) = o;
            }
            if (sub == 3) {   // zero cols 300..319
                short4v z = (short4v){0, 0, 0, 0};
                #pragma unroll
                for (int v = 75; v < 80; ++v)
                    *reinterpret_cast<short4v*>(&Xs[r][v * 4]) = z;
            }
        };
        stage(tid >> 2);
        if (tid < 12) stage(128 + (tid >> 2));
    }

    *reinterpret_cast<short8*>(&Bs[0][tid >> 2][(tid & 3) * 8]) = pb;
    __syncthreads();

    f32x4 acc[4][2];
    #pragma unroll
    for (int m = 0; m < 4; ++m)
        #pragma unroll
        for (int n = 0; n < 2; ++n)
            acc[m][n] = (f32x4){0.f, 0.f, 0.f, 0.f};

    int nch = W * 10;
    int buf = 0, ch = 0;
    for (int t = 0; t < W; ++t) {
        for (int cc = 0; cc < 10; ++cc, ++ch) {
            short8 nb;
            bool hn = (ch + 1 < nch);
            if (hn) nb = wp8[(ch + 1) * 512 + tid];
            short8 af[4], bv[2];
            #pragma unroll
            for (int m = 0; m < 4; ++m)
                af[m] = *reinterpret_cast<const short8*>(
                    &Xs[wr * 64 + m * 16 + (lane & 15) + t][cc * 32 + (lane >> 4) * 8]);
            #pragma unroll
            for (int n = 0; n < 2; ++n)
                bv[n] = *reinterpret_cast<const short8*>(
                    &Bs[buf][wc * 32 + n * 16 + (lane & 15)][(lane >> 4) * 8]);
            #pragma unroll
            for (int m = 0; m < 4; ++m)
                #pragma unroll
                for (int n = 0; n < 2; ++n)
                    acc[m][n] = __builtin_amdgcn_mfma_f32_16x16x32_bf16(af[m], bv[n], acc[m][n], 0, 0, 0);
            if (hn)
                *reinterpret_cast<short8*>(&Bs[buf ^ 1][tid >> 2][(tid & 3) * 8]) = nb;
            __syncthreads();
            buf ^= 1;
        }
    }

    // epilogue: bias + tanh, row l2-norm (shuffle within 16-lane groups + ssq combine)
    float ss[4][4];
    #pragma unroll
    for (int m = 0; m < 4; ++m)
        #pragma unroll
        for (int i = 0; i < 4; ++i) ss[m][i] = 0.f;

    #pragma unroll
    for (int n = 0; n < 2; ++n) {
        float bias = cb[wc * 32 + n * 16 + (lane & 15)];
        #pragma unroll
        for (int m = 0; m < 4; ++m)
            #pragma unroll
            for (int i = 0; i < 4; ++i) {
                float v = fast_tanh(acc[m][n][i] + bias);
                acc[m][n][i] = v;
                ss[m][i] += v * v;
            }
    }
    #pragma unroll
    for (int m = 0; m < 4; ++m)
        #pragma unroll
        for (int i = 0; i < 4; ++i) {
            float s = ss[m][i];
            s += __shfl_xor(s, 1); s += __shfl_xor(s, 2);
            s += __shfl_xor(s, 4); s += __shfl_xor(s, 8);
            ss[m][i] = s;
        }
    if ((lane & 15) == 0) {
        #pragma unroll
        for (int m = 0; m < 4; ++m)
            #pragma unroll
            for (int i = 0; i < 4; ++i)
                ssq[wc][wr * 64 + m * 16 + (lane >> 4) * 4 + i] = ss[m][i];
    }
    __syncthreads();
    #pragma unroll
    for (int m = 0; m < 4; ++m)
        #pragma unroll
        for (int i = 0; i < 4; ++i) {
            int row = wr * 64 + m * 16 + (lane >> 4) * 4 + i;
            float s2 = ssq[0][row] + ssq[1][row] + ssq[2][row] + ssq[3][row];
            float sc = 1.f / fmaxf(sqrtf(s2), 1e-12f);
            bf16* dst = outp + ((size_t)(b * L + l0 + row)) * NH;
            #pragma unroll
            for (int n = 0; n < 2; ++n) {
                int col = wc * 32 + n * 16 + (lane & 15);
                dst[col] = __float2bfloat16(acc[m][n][i] * sc);
            }
        }
}

// ---------------- Stage 2: S^T = D*Q^T, pooling fused on registers ----------
__global__ __launch_bounds__(256, 2)
void sim_kernel(const bf16* __restrict__ qn, const bf16* __restrict__ dn,
                float* __restrict__ phi)
{
    __shared__ bf16 Qs[128][136];
    __shared__ bf16 Ds[128][136];
    __shared__ float red[2][128][11];
    __shared__ float wsum[2][11];

    int blk = blockIdx.x;
    int b = blk / 9;
    int pair = blk - b * 9;
    int qi = pair / 3, di = pair - qi * 3;

    int tid = threadIdx.x, lane = tid & 63, wv = tid >> 6, wr = wv >> 1, wc = wv & 1;

    const bf16* qbase = qn + ((size_t)qi * NB + b) * (NLQ * NH);
    const bf16* dbase = dn + ((size_t)di * NB + b) * (NLD * NH);

    int r = tid >> 1, h0 = (tid & 1) * 64;

    #pragma unroll
    for (int v = 0; v < 8; ++v)
        *reinterpret_cast<short8*>(&Qs[r][h0 + v * 8]) =
            *reinterpret_cast<const short8*>(qbase + (size_t)r * NH + h0 + v * 8);

    {
        short8 st[8];
        #pragma unroll
        for (int v = 0; v < 8; ++v)
            st[v] = *reinterpret_cast<const short8*>(dbase + (size_t)r * NH + h0 + v * 8);
        #pragma unroll
        for (int v = 0; v < 8; ++v)
            *reinterpret_cast<short8*>(&Ds[r][h0 + v * 8]) = st[v];
    }
    __syncthreads();

    float sums[4][11];
    #pragma unroll
    for (int n = 0; n < 4; ++n)
        #pragma unroll
        for (int k = 0; k < 11; ++k) sums[n][k] = 0.f;

    for (int cc = 0; cc < 4; ++cc) {
        f32x4 acc[4][4];
        #pragma unroll
        for (int m = 0; m < 4; ++m)
            #pragma unroll
            for (int n = 0; n < 4; ++n)
                acc[m][n] = (f32x4){0.f, 0.f, 0.f, 0.f};

        #pragma unroll
        for (int kc = 0; kc < 4; ++kc) {
            short8 af[4], bq[4];
            #pragma unroll
            for (int m = 0; m < 4; ++m)
                af[m] = *reinterpret_cast<const short8*>(
                    &Ds[wr * 64 + m * 16 + (lane & 15)][kc * 32 + (lane >> 4) * 8]);
            #pragma unroll
            for (int n = 0; n < 4; ++n)
                bq[n] = *reinterpret_cast<const short8*>(
                    &Qs[wc * 64 + n * 16 + (lane & 15)][kc * 32 + (lane >> 4) * 8]);
            #pragma unroll
            for (int m = 0; m < 4; ++m)
                #pragma unroll
                for (int n = 0; n < 4; ++n)
                    acc[m][n] = __builtin_amdgcn_mfma_f32_16x16x32_bf16(af[m], bq[n], acc[m][n], 0, 0, 0);
        }
        __syncthreads();

        short8 st[8];
        if (cc < 3) {
            #pragma unroll
            for (int v = 0; v < 8; ++v)
                st[v] = *reinterpret_cast<const short8*>(
                    dbase + (size_t)((cc + 1) * 128 + r) * NH + h0 + v * 8);
        }

        #pragma unroll
        for (int n = 0; n < 4; ++n)
            #pragma unroll
            for (int m = 0; m < 4; ++m)
                #pragma unroll
                for (int i = 0; i < 4; ++i) {
                    float x = acc[m][n][i];
                    float ax2 = x * x * (-72.134752f);
                    #pragma unroll
                    for (int k = 0; k < 10; ++k) {
                        float mu = -0.9f + 0.2f * k;
                        float arg = ax2 + fmaf(144.26950408f * mu, x, -72.134752f * mu * mu);
                        sums[n][k] += __builtin_amdgcn_exp2f(arg);
                    }
                    float d = x - 1.0f;
                    sums[n][10] += __builtin_amdgcn_exp2f(d * d * (-721347.52f));
                }

        if (cc < 3) {
            #pragma unroll
            for (int v = 0; v < 8; ++v)
                *reinterpret_cast<short8*>(&Ds[r][h0 + v * 8]) = st[v];
            __syncthreads();
        }
    }

    #pragma unroll
    for (int n = 0; n < 4; ++n)
        #pragma unroll
        for (int k = 0; k < 11; ++k) {
            float s = sums[n][k];
            s += __shfl_xor(s, 16);
            s += __shfl_xor(s, 32);
            sums[n][k] = s;
        }
    if ((lane >> 4) == 0) {
        #pragma unroll
        for (int n = 0; n < 4; ++n)
            #pragma unroll
            for (int k = 0; k < 11; ++k)
                red[wr][wc * 64 + n * 16 + (lane & 15)][k] = sums[n][k];
    }
    __syncthreads();
    if (tid < 128) {
        float lv[11];
        #pragma unroll
        for (int k = 0; k < 11; ++k)
            lv[k] = log1pf(red[0][tid][k] + red[1][tid][k]);
        #pragma unroll
        for (int k = 0; k < 11; ++k) {
            float s = lv[k];
            s += __shfl_xor(s, 1); s += __shfl_xor(s, 2); s += __shfl_xor(s, 4);
            s += __shfl_xor(s, 8); s += __shfl_xor(s, 16); s += __shfl_xor(s, 32);
            lv[k] = s;
        }
        if ((tid & 63) == 0) {
            #pragma unroll
            for (int k = 0; k < 11; ++k) wsum[tid >> 6][k] = lv[k];
        }
    }
    __syncthreads();
    if (tid < 11) phi[b * 99 + pair * 11 + tid] = wsum[0][tid] + wsum[1][tid];
}

// ---------------- Stage 3: final linear ----------------
__global__ void final_kernel(const float* __restrict__ phi, const float* __restrict__ ow,
                             const float* __restrict__ obias, float* __restrict__ out)
{
    int b = threadIdx.x;
    float s = obias[0];
    #pragma unroll
    for (int j = 0; j < 99; ++j) s += phi[b * 99 + j] * ow[j];
    out[b] = s;
}

extern "C" void kernel_launch(void* const* d_in, const int* in_sizes, int n_in,
                              void* d_out, int out_size, void* d_ws, size_t ws_size,
                              hipStream_t stream)
{
    const int*   query = (const int*)d_in[0];
    const int*   doc   = (const int*)d_in[1];
    const float* q_emb = (const float*)d_in[2];
    const float* d_emb = (const float*)d_in[3];
    const float* out_w = (const float*)d_in[4];
    const float* out_b = (const float*)d_in[5];
    const float* cw0 = (const float*)d_in[6];
    const float* cb0 = (const float*)d_in[7];
    const float* cw1 = (const float*)d_in[8];
    const float* cb1 = (const float*)d_in[9];
    const float* cw2 = (const float*)d_in[10];
    const float* cb2 = (const float*)d_in[11];

    const size_t QN = (size_t)NB * NLQ * NH;
    const size_t DN = (size_t)NB * NLD * NH;

    bf16* Wp = (bf16*)d_ws;
    bf16* qn = Wp + 368640;
    bf16* dn = qn + 3 * QN;
    float* phi = (float*)(dn + 3 * DN);

    pack_w<<<dim3(640, 3), 256, 0, stream>>>(cw0, cw1, cw2, Wp);
    conv_kernel<<<1920, 512, 0, stream>>>(query, doc, q_emb, d_emb, Wp, cb0, cb1, cb2, qn, dn);
    sim_kernel<<<NB * 9, 256, 0, stream>>>(qn, dn, phi);
    final_kernel<<<1, 128, 0, stream>>>(phi, out_w, out_b, (float*)d_out);
}

// Round 5
// 290.561 us; speedup vs baseline: 4.6401x; 1.3734x over previous
//
#include <hip/hip_runtime.h>
#include <hip/hip_bf16.h>

typedef __hip_bfloat16 bf16;
typedef __attribute__((ext_vector_type(8))) short short8;
typedef __attribute__((ext_vector_type(4))) short short4v;
typedef __attribute__((ext_vector_type(4))) float f32x4;

#define NB 128
#define NH 128
#define NLQ 128
#define NLD 512
#define NEMB 300

__device__ __forceinline__ unsigned short bfbits(float x) {
    __hip_bfloat16 h = __float2bfloat16(x);
    return *reinterpret_cast<unsigned short*>(&h);
}

__device__ __forceinline__ float fast_tanh(float x) {
    x = fminf(9.f, fmaxf(-9.f, x));
    float e = __builtin_amdgcn_exp2f(x * 2.8853900817779268f); // e^{2x}
    return (e - 1.f) * __builtin_amdgcn_rcpf(e + 1.f);
}

// ---------------- Stage 0: pack conv weights, cc-major: [cc][t][h][c'] ------
__global__ void pack_w(const float* __restrict__ cw0, const float* __restrict__ cw1,
                       const float* __restrict__ cw2, bf16* __restrict__ Wp)
{
    int widx = blockIdx.y;
    int W = widx + 2;
    int e = blockIdx.x * 256 + threadIdx.x;
    if (e >= W * 40960) return;
    int ch = e >> 12;            // chunk = 4096 bf16
    int cc = ch / W;
    int t  = ch - cc * W;
    int h  = (e >> 5) & 127;
    int cp = e & 31;
    int c  = cc * 32 + cp;
    const float* cw = (widx == 0) ? cw0 : (widx == 1 ? cw1 : cw2);
    float v = (c < NEMB) ? cw[(h * NEMB + c) * W + t] : 0.f;
    size_t off = (widx == 0) ? 0 : (widx == 1 ? 81920 : 204800);
    Wp[off + e] = __float2bfloat16(v);
}

// ---------------- Stage 1: gather + conv + tanh + l2norm ----------------
// 256(l)x128(h) tile = 2 sub-sequences of 128 rows. 8 waves (4r x 2c), each 64x64.
// X streamed per-32-col chunk (dbuf, prefetch at t==0, write at t==W-1);
// B dbuf per step. LDS ~66KB -> 2 blocks/CU (4 waves/SIMD).
__global__ __launch_bounds__(512, 2)
void conv_kernel(const int* __restrict__ q_tok, const int* __restrict__ d_tok,
                 const float* __restrict__ q_emb, const float* __restrict__ d_emb,
                 const bf16* __restrict__ Wp,
                 const float* __restrict__ cb0, const float* __restrict__ cb1,
                 const float* __restrict__ cb2,
                 bf16* __restrict__ qn, bf16* __restrict__ dn)
{
    __shared__ bf16 Xs[2][2][132][40];   // [buf][subtile][row][col]; 80B rows, 16B-aligned
    __shared__ bf16 Bs[2][128][40];
    __shared__ int tokLds[2][132];
    __shared__ float ssq[2][256];

    int bx = blockIdx.x;
    int widx = bx % 3;
    int inner = bx / 3;
    int W = widx + 2;
    const bf16* wp = Wp + ((widx == 0) ? 0 : (widx == 1 ? 81920 : 204800));
    const float* cb = (widx == 0) ? cb0 : (widx == 1 ? cb1 : cb2);

    const int* toks; const float* emb; bf16* outp; int L;
    int sb0, sb1, sl00, sl01;
    if (inner < 64) {
        toks = q_tok; emb = q_emb; outp = qn + (size_t)widx * NB * NLQ * NH;
        L = NLQ; sb0 = inner * 2; sb1 = sb0 + 1; sl00 = 0; sl01 = 0;
    } else {
        int i = inner - 64;
        toks = d_tok; emb = d_emb; outp = dn + (size_t)widx * NB * NLD * NH;
        L = NLD; sb0 = i >> 1; sb1 = sb0; sl00 = (i & 1) * 256; sl01 = sl00 + 128;
    }

    int tid = threadIdx.x;
    int lane = tid & 63;
    int wv = tid >> 6;
    int wr = wv >> 1;     // 0..3 (row quarter)
    int wc = wv & 1;      // 0..1 (col half)
    int s_wave = wr >> 1;
    int lr_base = (wr & 1) * 64;

    // ---- tokens ----
    if (tid < 132) {
        int l = sl00 + tid;
        tokLds[0][tid] = (l < L) ? toks[sb0 * L + l] : -1;
    } else if (tid >= 256 && tid < 388) {
        int rr = tid - 256;
        int l = sl01 + rr;
        tokLds[1][rr] = (l < L) ? toks[sb1 * L + l] : -1;
    }
    __syncthreads();

    // ---- X staging helpers (main: 2 thr/row rows 0..255; tail: thr 448+ rows 128..131) ----
    auto xload_main = [&](int cc, float4* v) {
        int u = tid >> 1, s = u >> 7, rr = u & 127, half = tid & 1;
        int tok = tokLds[s][rr];
        int cbase = cc * 32 + half * 16;
        #pragma unroll
        for (int qq = 0; qq < 4; ++qq) {
            int c = cbase + qq * 4;
            float4 x = make_float4(0.f, 0.f, 0.f, 0.f);
            if (tok >= 0 && c < NEMB)
                x = *reinterpret_cast<const float4*>(emb + (size_t)tok * NEMB + c);
            v[qq] = x;
        }
    };
    auto xwrite_main = [&](int xb, const float4* v) {
        int u = tid >> 1, s = u >> 7, rr = u & 127, half = tid & 1;
        short8 o0, o1;
        o0[0] = (short)bfbits(v[0].x); o0[1] = (short)bfbits(v[0].y);
        o0[2] = (short)bfbits(v[0].z); o0[3] = (short)bfbits(v[0].w);
        o0[4] = (short)bfbits(v[1].x); o0[5] = (short)bfbits(v[1].y);
        o0[6] = (short)bfbits(v[1].z); o0[7] = (short)bfbits(v[1].w);
        o1[0] = (short)bfbits(v[2].x); o1[1] = (short)bfbits(v[2].y);
        o1[2] = (short)bfbits(v[2].z); o1[3] = (short)bfbits(v[2].w);
        o1[4] = (short)bfbits(v[3].x); o1[5] = (short)bfbits(v[3].y);
        o1[6] = (short)bfbits(v[3].z); o1[7] = (short)bfbits(v[3].w);
        *reinterpret_cast<short8*>(&Xs[xb][s][rr][half * 16]) = o0;
        *reinterpret_cast<short8*>(&Xs[xb][s][rr][half * 16 + 8]) = o1;
    };
    auto xload_tail = [&](int cc, float4& x) {
        int j = tid - 448, trow = j >> 3, s = trow >> 2, rr = 128 + (trow & 3), qq = j & 7;
        int tok = tokLds[s][rr];
        int c = cc * 32 + qq * 4;
        x = make_float4(0.f, 0.f, 0.f, 0.f);
        if (tok >= 0 && c < NEMB)
            x = *reinterpret_cast<const float4*>(emb + (size_t)tok * NEMB + c);
    };
    auto xwrite_tail = [&](int xb, const float4& x) {
        int j = tid - 448, trow = j >> 3, s = trow >> 2, rr = 128 + (trow & 3), qq = j & 7;
        short4v o;
        o[0] = (short)bfbits(x.x); o[1] = (short)bfbits(x.y);
        o[2] = (short)bfbits(x.z); o[3] = (short)bfbits(x.w);
        *reinterpret_cast<short4v*>(&Xs[xb][s][rr][qq * 4]) = o;
    };

    // ---- prologue: stage X chunk 0 + B step 0 ----
    const short8* wp8 = reinterpret_cast<const short8*>(wp);
    short8 pb = wp8[tid];
    {
        float4 v[4];
        xload_main(0, v);
        float4 xt;
        if (tid >= 448) xload_tail(0, xt);
        xwrite_main(0, v);
        if (tid >= 448) xwrite_tail(0, xt);
    }
    *reinterpret_cast<short8*>(&Bs[0][tid >> 2][(tid & 3) * 8]) = pb;
    __syncthreads();

    f32x4 acc[4][4];
    #pragma unroll
    for (int m = 0; m < 4; ++m)
        #pragma unroll
        for (int n = 0; n < 4; ++n)
            acc[m][n] = (f32x4){0.f, 0.f, 0.f, 0.f};

    int nsteps = W * 10;
    int bbuf = 0, xbuf = 0, step = 0;
    float4 xv[4]; float4 xtl;

    for (int cc = 0; cc < 10; ++cc) {
        for (int t = 0; t < W; ++t, ++step) {
            bool hn = (step + 1 < nsteps);
            short8 nb;
            if (hn) nb = wp8[(step + 1) * 512 + tid];
            if (t == 0 && cc < 9) {
                xload_main(cc + 1, xv);
                if (tid >= 448) xload_tail(cc + 1, xtl);
            }
            short8 bv[4];
            #pragma unroll
            for (int n = 0; n < 4; ++n)
                bv[n] = *reinterpret_cast<const short8*>(
                    &Bs[bbuf][wc * 64 + n * 16 + (lane & 15)][(lane >> 4) * 8]);
            #pragma unroll
            for (int m = 0; m < 4; ++m) {
                short8 af = *reinterpret_cast<const short8*>(
                    &Xs[xbuf][s_wave][lr_base + m * 16 + (lane & 15) + t][(lane >> 4) * 8]);
                #pragma unroll
                for (int n = 0; n < 4; ++n)
                    acc[m][n] = __builtin_amdgcn_mfma_f32_16x16x32_bf16(af, bv[n], acc[m][n], 0, 0, 0);
            }
            if (hn)
                *reinterpret_cast<short8*>(&Bs[bbuf ^ 1][tid >> 2][(tid & 3) * 8]) = nb;
            if (t == W - 1 && cc < 9) {
                xwrite_main(xbuf ^ 1, xv);
                if (tid >= 448) xwrite_tail(xbuf ^ 1, xtl);
            }
            __syncthreads();
            bbuf ^= 1;
            if (t == W - 1) xbuf ^= 1;
        }
    }

    // ---- epilogue: bias + tanh, row l2norm, store ----
    float ssl[4][4];
    #pragma unroll
    for (int m = 0; m < 4; ++m)
        #pragma unroll
        for (int i = 0; i < 4; ++i) ssl[m][i] = 0.f;

    #pragma unroll
    for (int n = 0; n < 4; ++n) {
        float bias = cb[wc * 64 + n * 16 + (lane & 15)];
        #pragma unroll
        for (int m = 0; m < 4; ++m)
            #pragma unroll
            for (int i = 0; i < 4; ++i) {
                float v = fast_tanh(acc[m][n][i] + bias);
                acc[m][n][i] = v;
                ssl[m][i] += v * v;
            }
    }
    #pragma unroll
    for (int m = 0; m < 4; ++m)
        #pragma unroll
        for (int i = 0; i < 4; ++i) {
            float s = ssl[m][i];
            s += __shfl_xor(s, 1); s += __shfl_xor(s, 2);
            s += __shfl_xor(s, 4); s += __shfl_xor(s, 8);
            ssl[m][i] = s;
        }
    if ((lane & 15) == 0) {
        #pragma unroll
        for (int m = 0; m < 4; ++m)
            #pragma unroll
            for (int i = 0; i < 4; ++i)
                ssq[wc][wr * 64 + m * 16 + (lane >> 4) * 4 + i] = ssl[m][i];
    }
    __syncthreads();
    #pragma unroll
    for (int m = 0; m < 4; ++m)
        #pragma unroll
        for (int i = 0; i < 4; ++i) {
            int r = wr * 64 + m * 16 + (lane >> 4) * 4 + i;
            float s2 = ssq[0][r] + ssq[1][r];
            float sc = 1.f / fmaxf(sqrtf(s2), 1e-12f);
            int s = r >> 7, lr = r & 127;
            int b = s ? sb1 : sb0;
            int l = (s ? sl01 : sl00) + lr;
            bf16* dst = outp + ((size_t)(b * L + l)) * NH;
            #pragma unroll
            for (int n = 0; n < 4; ++n)
                dst[wc * 64 + n * 16 + (lane & 15)] = __float2bfloat16(acc[m][n][i] * sc);
        }
}

// ---------------- Stage 2: S^T = D*Q^T, recurrence-based pooling ----------
__global__ __launch_bounds__(256, 2)
void sim_kernel(const bf16* __restrict__ qn, const bf16* __restrict__ dn,
                float* __restrict__ phi)
{
    __shared__ bf16 Qs[128][136];
    __shared__ bf16 Ds[128][136];
    __shared__ float red[2][128][11];
    __shared__ float wsum[2][11];

    int blk = blockIdx.x;
    int b = blk / 9;
    int pair = blk - b * 9;
    int qi = pair / 3, di = pair - qi * 3;

    int tid = threadIdx.x, lane = tid & 63, wv = tid >> 6, wr = wv >> 1, wc = wv & 1;

    const bf16* qbase = qn + ((size_t)qi * NB + b) * (NLQ * NH);
    const bf16* dbase = dn + ((size_t)di * NB + b) * (NLD * NH);

    int r = tid >> 1, h0 = (tid & 1) * 64;

    #pragma unroll
    for (int v = 0; v < 8; ++v)
        *reinterpret_cast<short8*>(&Qs[r][h0 + v * 8]) =
            *reinterpret_cast<const short8*>(qbase + (size_t)r * NH + h0 + v * 8);

    {
        short8 st[8];
        #pragma unroll
        for (int v = 0; v < 8; ++v)
            st[v] = *reinterpret_cast<const short8*>(dbase + (size_t)r * NH + h0 + v * 8);
        #pragma unroll
        for (int v = 0; v < 8; ++v)
            *reinterpret_cast<short8*>(&Ds[r][h0 + v * 8]) = st[v];
    }
    __syncthreads();

    float sums[4][11];
    #pragma unroll
    for (int n = 0; n < 4; ++n)
        #pragma unroll
        for (int k = 0; k < 11; ++k) sums[n][k] = 0.f;

    const float C1 = 1.8315638888734179e-2f;   // e^-4
    const float C2 = 3.3546262790251185e-4f;   // e^-8
    const float C3 = 6.1442123533282098e-6f;   // e^-12
    const float C4 = 1.1253517471925912e-7f;   // e^-16

    for (int cc = 0; cc < 4; ++cc) {
        f32x4 acc[4][4];
        #pragma unroll
        for (int m = 0; m < 4; ++m)
            #pragma unroll
            for (int n = 0; n < 4; ++n)
                acc[m][n] = (f32x4){0.f, 0.f, 0.f, 0.f};

        #pragma unroll
        for (int kc = 0; kc < 4; ++kc) {
            short8 af[4], bq[4];
            #pragma unroll
            for (int m = 0; m < 4; ++m)
                af[m] = *reinterpret_cast<const short8*>(
                    &Ds[wr * 64 + m * 16 + (lane & 15)][kc * 32 + (lane >> 4) * 8]);
            #pragma unroll
            for (int n = 0; n < 4; ++n)
                bq[n] = *reinterpret_cast<const short8*>(
                    &Qs[wc * 64 + n * 16 + (lane & 15)][kc * 32 + (lane >> 4) * 8]);
            #pragma unroll
            for (int m = 0; m < 4; ++m)
                #pragma unroll
                for (int n = 0; n < 4; ++n)
                    acc[m][n] = __builtin_amdgcn_mfma_f32_16x16x32_bf16(af[m], bq[n], acc[m][n], 0, 0, 0);
        }
        __syncthreads();

        short8 st[8];
        if (cc < 3) {
            #pragma unroll
            for (int v = 0; v < 8; ++v)
                st[v] = *reinterpret_cast<const short8*>(
                    dbase + (size_t)((cc + 1) * 128 + r) * NH + h0 + v * 8);
        }

        // Gaussian soft-histogram via recurrence: E_{k+1} = E_k * e^{20x} * e^{16-4k},
        // computed outward from k=4 (middle) to keep f32 range.
        #pragma unroll
        for (int n = 0; n < 4; ++n)
            #pragma unroll
            for (int m = 0; m < 4; ++m)
                #pragma unroll
                for (int i = 0; i < 4; ++i) {
                    float x = acc[m][n][i];
                    float R  = __builtin_amdgcn_exp2f(x * 28.853900817779268f);   // e^{20x}
                    float Ri = __builtin_amdgcn_exp2f(x * -28.853900817779268f);  // e^{-20x}
                    float d4 = x + 0.1f;
                    float E4 = __builtin_amdgcn_exp2f(d4 * d4 * -72.134752044448169f);
                    sums[n][4] += E4;
                    float u = E4 * R;        sums[n][5] += u;
                    u *= R; u *= C1;         sums[n][6] += u;
                    u *= R; u *= C2;         sums[n][7] += u;
                    u *= R; u *= C3;         sums[n][8] += u;
                    u *= R; u *= C4;         sums[n][9] += u;
                    float w = E4 * Ri; w *= C1; sums[n][3] += w;
                    w *= Ri; w *= C2;        sums[n][2] += w;
                    w *= Ri; w *= C3;        sums[n][1] += w;
                    w *= Ri; w *= C4;        sums[n][0] += w;
                    float d1 = x - 1.0f;
                    sums[n][10] += __builtin_amdgcn_exp2f(d1 * d1 * -721347.52044448f);
                }

        if (cc < 3) {
            #pragma unroll
            for (int v = 0; v < 8; ++v)
                *reinterpret_cast<short8*>(&Ds[r][h0 + v * 8]) = st[v];
            __syncthreads();
        }
    }

    #pragma unroll
    for (int n = 0; n < 4; ++n)
        #pragma unroll
        for (int k = 0; k < 11; ++k) {
            float s = sums[n][k];
            s += __shfl_xor(s, 16);
            s += __shfl_xor(s, 32);
            sums[n][k] = s;
        }
    if ((lane >> 4) == 0) {
        #pragma unroll
        for (int n = 0; n < 4; ++n)
            #pragma unroll
            for (int k = 0; k < 11; ++k)
                red[wr][wc * 64 + n * 16 + (lane & 15)][k] = sums[n][k];
    }
    __syncthreads();
    if (tid < 128) {
        float lv[11];
        #pragma unroll
        for (int k = 0; k < 11; ++k)
            lv[k] = log1pf(red[0][tid][k] + red[1][tid][k]);
        #pragma unroll
        for (int k = 0; k < 11; ++k) {
            float s = lv[k];
            s += __shfl_xor(s, 1); s += __shfl_xor(s, 2); s += __shfl_xor(s, 4);
            s += __shfl_xor(s, 8); s += __shfl_xor(s, 16); s += __shfl_xor(s, 32);
            lv[k] = s;
        }
        if ((tid & 63) == 0) {
            #pragma unroll
            for (int k = 0; k < 11; ++k) wsum[tid >> 6][k] = lv[k];
        }
    }
    __syncthreads();
    if (tid < 11) phi[b * 99 + pair * 11 + tid] = wsum[0][tid] + wsum[1][tid];
}

// ---------------- Stage 3: final linear ----------------
__global__ void final_kernel(const float* __restrict__ phi, const float* __restrict__ ow,
                             const float* __restrict__ obias, float* __restrict__ out)
{
    int b = threadIdx.x;
    float s = obias[0];
    #pragma unroll
    for (int j = 0; j < 99; ++j) s += phi[b * 99 + j] * ow[j];
    out[b] = s;
}

extern "C" void kernel_launch(void* const* d_in, const int* in_sizes, int n_in,
                              void* d_out, int out_size, void* d_ws, size_t ws_size,
                              hipStream_t stream)
{
    const int*   query = (const int*)d_in[0];
    const int*   doc   = (const int*)d_in[1];
    const float* q_emb = (const float*)d_in[2];
    const float* d_emb = (const float*)d_in[3];
    const float* out_w = (const float*)d_in[4];
    const float* out_b = (const float*)d_in[5];
    const float* cw0 = (const float*)d_in[6];
    const float* cb0 = (const float*)d_in[7];
    const float* cw1 = (const float*)d_in[8];
    const float* cb1 = (const float*)d_in[9];
    const float* cw2 = (const float*)d_in[10];
    const float* cb2 = (const float*)d_in[11];

    const size_t QN = (size_t)NB * NLQ * NH;
    const size_t DN = (size_t)NB * NLD * NH;

    bf16* Wp = (bf16*)d_ws;
    bf16* qn = Wp + 368640;
    bf16* dn = qn + 3 * QN;
    float* phi = (float*)(dn + 3 * DN);

    pack_w<<<dim3(640, 3), 256, 0, stream>>>(cw0, cw1, cw2, Wp);
    conv_kernel<<<960, 512, 0, stream>>>(query, doc, q_emb, d_emb, Wp, cb0, cb1, cb2, qn, dn);
    sim_kernel<<<NB * 9, 256, 0, stream>>>(qn, dn, phi);
    final_kernel<<<1, 128, 0, stream>>>(phi, out_w, out_b, (float*)d_out);
}

// Round 6
// 264.226 us; speedup vs baseline: 5.1026x; 1.0997x over previous
//
#include <hip/hip_runtime.h>
#include <hip/hip_bf16.h>

typedef __hip_bfloat16 bf16;
typedef __attribute__((ext_vector_type(8))) short short8;
typedef __attribute__((ext_vector_type(4))) short short4v;
typedef __attribute__((ext_vector_type(4))) float f32x4;

#define NB 128
#define NH 128
#define NLQ 128
#define NLD 512
#define NEMB 300

__device__ __forceinline__ unsigned short bfbits(float x) {
    __hip_bfloat16 h = __float2bfloat16(x);
    return *reinterpret_cast<unsigned short*>(&h);
}

__device__ __forceinline__ float fast_tanh(float x) {
    x = fminf(9.f, fmaxf(-9.f, x));
    float e = __builtin_amdgcn_exp2f(x * 2.8853900817779268f); // e^{2x}
    return (e - 1.f) * __builtin_amdgcn_rcpf(e + 1.f);
}

// ---------------- Stage 0: pack conv weights, cc-major: [cc][t][h][c'] ------
__global__ void pack_w(const float* __restrict__ cw0, const float* __restrict__ cw1,
                       const float* __restrict__ cw2, bf16* __restrict__ Wp)
{
    int widx = blockIdx.y;
    int W = widx + 2;
    int e = blockIdx.x * 256 + threadIdx.x;
    if (e >= W * 40960) return;
    int ch = e >> 12;            // chunk = 4096 bf16
    int cc = ch / W;
    int t  = ch - cc * W;
    int h  = (e >> 5) & 127;
    int cp = e & 31;
    int c  = cc * 32 + cp;
    const float* cw = (widx == 0) ? cw0 : (widx == 1 ? cw1 : cw2);
    float v = (c < NEMB) ? cw[(h * NEMB + c) * W + t] : 0.f;
    size_t off = (widx == 0) ? 0 : (widx == 1 ? 81920 : 204800);
    Wp[off + e] = __float2bfloat16(v);
}

// ---------------- Stage 1: gather + conv + tanh + l2norm ----------------
// 256(l)x128(h) tile, 8 waves (4r x 2c) of 64x64. X single-buffered (reg
// prefetch at t==0, write after extra barrier at t==W-1); B dbuf.
// LDS ~44.7KB -> 3 blocks/CU.
__global__ __launch_bounds__(512, 4)
void conv_kernel(const int* __restrict__ q_tok, const int* __restrict__ d_tok,
                 const float* __restrict__ q_emb, const float* __restrict__ d_emb,
                 const bf16* __restrict__ Wp,
                 const float* __restrict__ cb0, const float* __restrict__ cb1,
                 const float* __restrict__ cb2,
                 bf16* __restrict__ qn, bf16* __restrict__ dn)
{
    __shared__ bf16 Xs[2][132][40];      // [subtile][row][col]; single K-chunk buffer
    __shared__ bf16 Bs[2][128][40];
    __shared__ int tokLds[2][132];
    __shared__ float ssq[2][256];

    int bx = blockIdx.x;
    int widx = bx % 3;
    int inner = bx / 3;
    int W = widx + 2;
    const bf16* wp = Wp + ((widx == 0) ? 0 : (widx == 1 ? 81920 : 204800));
    const float* cb = (widx == 0) ? cb0 : (widx == 1 ? cb1 : cb2);

    const int* toks; const float* emb; bf16* outp; int L;
    int sb0, sb1, sl00, sl01;
    if (inner < 64) {
        toks = q_tok; emb = q_emb; outp = qn + (size_t)widx * NB * NLQ * NH;
        L = NLQ; sb0 = inner * 2; sb1 = sb0 + 1; sl00 = 0; sl01 = 0;
    } else {
        int i = inner - 64;
        toks = d_tok; emb = d_emb; outp = dn + (size_t)widx * NB * NLD * NH;
        L = NLD; sb0 = i >> 1; sb1 = sb0; sl00 = (i & 1) * 256; sl01 = sl00 + 128;
    }

    int tid = threadIdx.x;
    int lane = tid & 63;
    int wv = tid >> 6;
    int wr = wv >> 1;     // 0..3 (row quarter)
    int wc = wv & 1;      // 0..1 (col half)
    int s_wave = wr >> 1;
    int lr_base = (wr & 1) * 64;

    // ---- tokens ----
    if (tid < 132) {
        int l = sl00 + tid;
        tokLds[0][tid] = (l < L) ? toks[sb0 * L + l] : -1;
    } else if (tid >= 256 && tid < 388) {
        int rr = tid - 256;
        int l = sl01 + rr;
        tokLds[1][rr] = (l < L) ? toks[sb1 * L + l] : -1;
    }
    __syncthreads();

    // ---- X staging helpers (main: 2 thr/row rows 0..255; tail: thr 448+ rows 128..131) ----
    auto xload_main = [&](int cc, float4* v) {
        int u = tid >> 1, s = u >> 7, rr = u & 127, half = tid & 1;
        int tok = tokLds[s][rr];
        int cbase = cc * 32 + half * 16;
        #pragma unroll
        for (int qq = 0; qq < 4; ++qq) {
            int c = cbase + qq * 4;
            float4 x = make_float4(0.f, 0.f, 0.f, 0.f);
            if (tok >= 0 && c < NEMB)
                x = *reinterpret_cast<const float4*>(emb + (size_t)tok * NEMB + c);
            v[qq] = x;
        }
    };
    auto xwrite_main = [&](const float4* v) {
        int u = tid >> 1, s = u >> 7, rr = u & 127, half = tid & 1;
        short8 o0, o1;
        o0[0] = (short)bfbits(v[0].x); o0[1] = (short)bfbits(v[0].y);
        o0[2] = (short)bfbits(v[0].z); o0[3] = (short)bfbits(v[0].w);
        o0[4] = (short)bfbits(v[1].x); o0[5] = (short)bfbits(v[1].y);
        o0[6] = (short)bfbits(v[1].z); o0[7] = (short)bfbits(v[1].w);
        o1[0] = (short)bfbits(v[2].x); o1[1] = (short)bfbits(v[2].y);
        o1[2] = (short)bfbits(v[2].z); o1[3] = (short)bfbits(v[2].w);
        o1[4] = (short)bfbits(v[3].x); o1[5] = (short)bfbits(v[3].y);
        o1[6] = (short)bfbits(v[3].z); o1[7] = (short)bfbits(v[3].w);
        *reinterpret_cast<short8*>(&Xs[s][rr][half * 16]) = o0;
        *reinterpret_cast<short8*>(&Xs[s][rr][half * 16 + 8]) = o1;
    };
    auto xload_tail = [&](int cc, float4& x) {
        int j = tid - 448, trow = j >> 3, s = trow >> 2, rr = 128 + (trow & 3), qq = j & 7;
        int tok = tokLds[s][rr];
        int c = cc * 32 + qq * 4;
        x = make_float4(0.f, 0.f, 0.f, 0.f);
        if (tok >= 0 && c < NEMB)
            x = *reinterpret_cast<const float4*>(emb + (size_t)tok * NEMB + c);
    };
    auto xwrite_tail = [&](const float4& x) {
        int j = tid - 448, trow = j >> 3, s = trow >> 2, rr = 128 + (trow & 3), qq = j & 7;
        short4v o;
        o[0] = (short)bfbits(x.x); o[1] = (short)bfbits(x.y);
        o[2] = (short)bfbits(x.z); o[3] = (short)bfbits(x.w);
        *reinterpret_cast<short4v*>(&Xs[s][rr][qq * 4]) = o;
    };

    // ---- prologue: stage X chunk 0 + B step 0 ----
    const short8* wp8 = reinterpret_cast<const short8*>(wp);
    short8 pb = wp8[tid];
    {
        float4 v[4];
        xload_main(0, v);
        float4 xt;
        if (tid >= 448) xload_tail(0, xt);
        xwrite_main(v);
        if (tid >= 448) xwrite_tail(xt);
    }
    *reinterpret_cast<short8*>(&Bs[0][tid >> 2][(tid & 3) * 8]) = pb;
    __syncthreads();

    f32x4 acc[4][4];
    #pragma unroll
    for (int m = 0; m < 4; ++m)
        #pragma unroll
        for (int n = 0; n < 4; ++n)
            acc[m][n] = (f32x4){0.f, 0.f, 0.f, 0.f};

    int nsteps = W * 10;
    int bbuf = 0, step = 0;
    float4 xv[4]; float4 xtl;

    for (int cc = 0; cc < 10; ++cc) {
        for (int t = 0; t < W; ++t, ++step) {
            bool hn = (step + 1 < nsteps);
            short8 nb;
            if (hn) nb = wp8[(step + 1) * 512 + tid];
            if (t == 0 && cc < 9) {
                xload_main(cc + 1, xv);
                if (tid >= 448) xload_tail(cc + 1, xtl);
            }
            short8 bv[4];
            #pragma unroll
            for (int n = 0; n < 4; ++n)
                bv[n] = *reinterpret_cast<const short8*>(
                    &Bs[bbuf][wc * 64 + n * 16 + (lane & 15)][(lane >> 4) * 8]);
            #pragma unroll
            for (int m = 0; m < 4; ++m) {
                short8 af = *reinterpret_cast<const short8*>(
                    &Xs[s_wave][lr_base + m * 16 + (lane & 15) + t][(lane >> 4) * 8]);
                #pragma unroll
                for (int n = 0; n < 4; ++n)
                    acc[m][n] = __builtin_amdgcn_mfma_f32_16x16x32_bf16(af, bv[n], acc[m][n], 0, 0, 0);
            }
            if (hn)
                *reinterpret_cast<short8*>(&Bs[bbuf ^ 1][tid >> 2][(tid & 3) * 8]) = nb;
            __syncthreads();
            bbuf ^= 1;
            if (t == W - 1 && cc < 9) {
                // all reads of Xs for this cc are behind the barrier above
                xwrite_main(xv);
                if (tid >= 448) xwrite_tail(xtl);
                __syncthreads();
            }
        }
    }

    // ---- epilogue: bias + tanh, row l2norm, store ----
    float ssl[4][4];
    #pragma unroll
    for (int m = 0; m < 4; ++m)
        #pragma unroll
        for (int i = 0; i < 4; ++i) ssl[m][i] = 0.f;

    #pragma unroll
    for (int n = 0; n < 4; ++n) {
        float bias = cb[wc * 64 + n * 16 + (lane & 15)];
        #pragma unroll
        for (int m = 0; m < 4; ++m)
            #pragma unroll
            for (int i = 0; i < 4; ++i) {
                float v = fast_tanh(acc[m][n][i] + bias);
                acc[m][n][i] = v;
                ssl[m][i] += v * v;
            }
    }
    #pragma unroll
    for (int m = 0; m < 4; ++m)
        #pragma unroll
        for (int i = 0; i < 4; ++i) {
            float s = ssl[m][i];
            s += __shfl_xor(s, 1); s += __shfl_xor(s, 2);
            s += __shfl_xor(s, 4); s += __shfl_xor(s, 8);
            ssl[m][i] = s;
        }
    if ((lane & 15) == 0) {
        #pragma unroll
        for (int m = 0; m < 4; ++m)
            #pragma unroll
            for (int i = 0; i < 4; ++i)
                ssq[wc][wr * 64 + m * 16 + (lane >> 4) * 4 + i] = ssl[m][i];
    }
    __syncthreads();
    #pragma unroll
    for (int m = 0; m < 4; ++m)
        #pragma unroll
        for (int i = 0; i < 4; ++i) {
            int r = wr * 64 + m * 16 + (lane >> 4) * 4 + i;
            float s2 = ssq[0][r] + ssq[1][r];
            float sc = 1.f / fmaxf(sqrtf(s2), 1e-12f);
            int s = r >> 7, lr = r & 127;
            int b = s ? sb1 : sb0;
            int l = (s ? sl01 : sl00) + lr;
            bf16* dst = outp + ((size_t)(b * L + l)) * NH;
            #pragma unroll
            for (int n = 0; n < 4; ++n)
                dst[wc * 64 + n * 16 + (lane & 15)] = __float2bfloat16(acc[m][n][i] * sc);
        }
}

// ---------------- Stage 2: S^T = D*Q^T, recurrence pooling ----------
// 8 chunks of 64 d-rows; red aliases Ds; LDS ~52.3KB -> 3 blocks/CU.
__global__ __launch_bounds__(256, 4)
void sim_kernel(const bf16* __restrict__ qn, const bf16* __restrict__ dn,
                float* __restrict__ phi)
{
    __shared__ bf16 Qs[128][136];
    __shared__ bf16 Ds[64][136];
    __shared__ float wsum[2][11];
    float (*red)[128][11] = reinterpret_cast<float(*)[128][11]>(&Ds[0][0]); // alias (disjoint in time)

    int blk = blockIdx.x;
    int b = blk / 9;
    int pair = blk - b * 9;
    int qi = pair / 3, di = pair - qi * 3;

    int tid = threadIdx.x, lane = tid & 63, wv = tid >> 6, wr = wv >> 1, wc = wv & 1;

    const bf16* qbase = qn + ((size_t)qi * NB + b) * (NLQ * NH);
    const bf16* dbase = dn + ((size_t)di * NB + b) * (NLD * NH);

    // stage Q (128x128): 2 thr/row
    {
        int r = tid >> 1, h0 = (tid & 1) * 64;
        #pragma unroll
        for (int v = 0; v < 8; ++v)
            *reinterpret_cast<short8*>(&Qs[r][h0 + v * 8]) =
                *reinterpret_cast<const short8*>(qbase + (size_t)r * NH + h0 + v * 8);
    }

    // stage D chunk 0 (64 rows): 4 thr/row
    int dr = tid >> 2, dc = (tid & 3) * 32;
    {
        short8 st[4];
        #pragma unroll
        for (int v = 0; v < 4; ++v)
            st[v] = *reinterpret_cast<const short8*>(dbase + (size_t)dr * NH + dc + v * 8);
        #pragma unroll
        for (int v = 0; v < 4; ++v)
            *reinterpret_cast<short8*>(&Ds[dr][dc + v * 8]) = st[v];
    }
    __syncthreads();

    float sums[4][11];
    #pragma unroll
    for (int n = 0; n < 4; ++n)
        #pragma unroll
        for (int k = 0; k < 11; ++k) sums[n][k] = 0.f;

    const float C1 = 1.8315638888734179e-2f;   // e^-4
    const float C2 = 3.3546262790251185e-4f;   // e^-8
    const float C3 = 6.1442123533282098e-6f;   // e^-12
    const float C4 = 1.1253517471925912e-7f;   // e^-16

    for (int cc = 0; cc < 8; ++cc) {
        f32x4 acc[2][4];
        #pragma unroll
        for (int m = 0; m < 2; ++m)
            #pragma unroll
            for (int n = 0; n < 4; ++n)
                acc[m][n] = (f32x4){0.f, 0.f, 0.f, 0.f};

        #pragma unroll
        for (int kc = 0; kc < 4; ++kc) {
            short8 af[2], bq[4];
            #pragma unroll
            for (int m = 0; m < 2; ++m)
                af[m] = *reinterpret_cast<const short8*>(
                    &Ds[wr * 32 + m * 16 + (lane & 15)][kc * 32 + (lane >> 4) * 8]);
            #pragma unroll
            for (int n = 0; n < 4; ++n)
                bq[n] = *reinterpret_cast<const short8*>(
                    &Qs[wc * 64 + n * 16 + (lane & 15)][kc * 32 + (lane >> 4) * 8]);
            #pragma unroll
            for (int m = 0; m < 2; ++m)
                #pragma unroll
                for (int n = 0; n < 4; ++n)
                    acc[m][n] = __builtin_amdgcn_mfma_f32_16x16x32_bf16(af[m], bq[n], acc[m][n], 0, 0, 0);
        }
        __syncthreads();   // Ds reads done

        short8 st[4];
        if (cc < 7) {
            #pragma unroll
            for (int v = 0; v < 4; ++v)
                st[v] = *reinterpret_cast<const short8*>(
                    dbase + (size_t)((cc + 1) * 64 + dr) * NH + dc + v * 8);
        }

        // Gaussian soft-histogram via recurrence outward from k=4.
        #pragma unroll
        for (int n = 0; n < 4; ++n)
            #pragma unroll
            for (int m = 0; m < 2; ++m)
                #pragma unroll
                for (int i = 0; i < 4; ++i) {
                    float x = acc[m][n][i];
                    float R  = __builtin_amdgcn_exp2f(x * 28.853900817779268f);   // e^{20x}
                    float Ri = __builtin_amdgcn_exp2f(x * -28.853900817779268f);  // e^{-20x}
                    float d4 = x + 0.1f;
                    float E4 = __builtin_amdgcn_exp2f(d4 * d4 * -72.134752044448169f);
                    sums[n][4] += E4;
                    float u = E4 * R;        sums[n][5] += u;
                    u *= R; u *= C1;         sums[n][6] += u;
                    u *= R; u *= C2;         sums[n][7] += u;
                    u *= R; u *= C3;         sums[n][8] += u;
                    u *= R; u *= C4;         sums[n][9] += u;
                    float w = E4 * Ri; w *= C1; sums[n][3] += w;
                    w *= Ri; w *= C2;        sums[n][2] += w;
                    w *= Ri; w *= C3;        sums[n][1] += w;
                    w *= Ri; w *= C4;        sums[n][0] += w;
                    float d1 = x - 1.0f;
                    sums[n][10] += __builtin_amdgcn_exp2f(d1 * d1 * -721347.52044448f);
                }

        if (cc < 7) {
            #pragma unroll
            for (int v = 0; v < 4; ++v)
                *reinterpret_cast<short8*>(&Ds[dr][dc + v * 8]) = st[v];
            __syncthreads();
        }
    }

    // reduce over d-row groups, combine wr halves (red aliases Ds -- safe now)
    #pragma unroll
    for (int n = 0; n < 4; ++n)
        #pragma unroll
        for (int k = 0; k < 11; ++k) {
            float s = sums[n][k];
            s += __shfl_xor(s, 16);
            s += __shfl_xor(s, 32);
            sums[n][k] = s;
        }
    if ((lane >> 4) == 0) {
        #pragma unroll
        for (int n = 0; n < 4; ++n)
            #pragma unroll
            for (int k = 0; k < 11; ++k)
                red[wr][wc * 64 + n * 16 + (lane & 15)][k] = sums[n][k];
    }
    __syncthreads();
    if (tid < 128) {
        float lv[11];
        #pragma unroll
        for (int k = 0; k < 11; ++k)
            lv[k] = log1pf(red[0][tid][k] + red[1][tid][k]);
        #pragma unroll
        for (int k = 0; k < 11; ++k) {
            float s = lv[k];
            s += __shfl_xor(s, 1); s += __shfl_xor(s, 2); s += __shfl_xor(s, 4);
            s += __shfl_xor(s, 8); s += __shfl_xor(s, 16); s += __shfl_xor(s, 32);
            lv[k] = s;
        }
        if ((tid & 63) == 0) {
            #pragma unroll
            for (int k = 0; k < 11; ++k) wsum[tid >> 6][k] = lv[k];
        }
    }
    __syncthreads();
    if (tid < 11) phi[b * 99 + pair * 11 + tid] = wsum[0][tid] + wsum[1][tid];
}

// ---------------- Stage 3: final linear ----------------
__global__ void final_kernel(const float* __restrict__ phi, const float* __restrict__ ow,
                             const float* __restrict__ obias, float* __restrict__ out)
{
    int b = threadIdx.x;
    float s = obias[0];
    #pragma unroll
    for (int j = 0; j < 99; ++j) s += phi[b * 99 + j] * ow[j];
    out[b] = s;
}

extern "C" void kernel_launch(void* const* d_in, const int* in_sizes, int n_in,
                              void* d_out, int out_size, void* d_ws, size_t ws_size,
                              hipStream_t stream)
{
    const int*   query = (const int*)d_in[0];
    const int*   doc   = (const int*)d_in[1];
    const float* q_emb = (const float*)d_in[2];
    const float* d_emb = (const float*)d_in[3];
    const float* out_w = (const float*)d_in[4];
    const float* out_b = (const float*)d_in[5];
    const float* cw0 = (const float*)d_in[6];
    const float* cb0 = (const float*)d_in[7];
    const float* cw1 = (const float*)d_in[8];
    const float* cb1 = (const float*)d_in[9];
    const float* cw2 = (const float*)d_in[10];
    const float* cb2 = (const float*)d_in[11];

    const size_t QN = (size_t)NB * NLQ * NH;
    const size_t DN = (size_t)NB * NLD * NH;

    bf16* Wp = (bf16*)d_ws;
    bf16* qn = Wp + 368640;
    bf16* dn = qn + 3 * QN;
    float* phi = (float*)(dn + 3 * DN);

    pack_w<<<dim3(640, 3), 256, 0, stream>>>(cw0, cw1, cw2, Wp);
    conv_kernel<<<960, 512, 0, stream>>>(query, doc, q_emb, d_emb, Wp, cb0, cb1, cb2, qn, dn);
    sim_kernel<<<NB * 9, 256, 0, stream>>>(qn, dn, phi);
    final_kernel<<<1, 128, 0, stream>>>(phi, out_w, out_b, (float*)d_out);
}